// Round 5
// baseline (160.951 us; speedup 1.0000x reference)
//
#include <hip/hip_runtime.h>
#include <math.h>

#define EPS_F 1e-6f

// ---- workspace layout (float offsets), ~4.8 MB ----
#define OFF_WCQ 0                          // folded q weights [256][256]
#define OFF_WCK (OFF_WCQ + 65536)          // folded k weights [256][256]
#define OFF_BV  (OFF_WCK + 65536)          // folded v bias [256]
#define OFF_VC  (OFF_BV + 256)             // dwconv output [256][4096]
#define OFF_SM  (OFF_VC + 256*4096)        // Sm [8][64*64]  (atomic-accumulated)
#define OFF_SV  (OFF_SM + 8*4096)          // sv [8][64]

// blocks 0..255: fold hedgehog into 1x1x1 conv weights + zero Sm/sv.
// blocks 256..4351: depthwise 3x3x3 conv (z-plane per block).
__global__ __launch_bounds__(256) void k_prep(
    const float* __restrict__ x,  const float* __restrict__ Wv,
    const float* __restrict__ Wq, const float* __restrict__ Wk,
    const float* __restrict__ Wmq, const float* __restrict__ Wmk,
    const float* __restrict__ Wmv, const float* __restrict__ bmv,
    const float* __restrict__ bv, float* __restrict__ ws)
{
    int b = blockIdx.x, t = threadIdx.x;
    if (b < 256) {
        int gid = b*256 + t;
        if (gid < 8*4096 + 512) ws[OFF_SM + gid] = 0.f;   // zero Sm + sv
        int h = b >> 6, e = b & 63;
        float aq = 0.f, ak = 0.f;
        for (int d = 0; d < 64; ++d) {
            float mq = Wmq[e*64 + d];
            float mk = Wmk[e*64 + d];
            int src = (h*64 + d)*256 + t;
            aq = fmaf(mq, Wq[src], aq);
            ak = fmaf(mk, Wk[src], ak);
        }
        ws[OFF_WCQ + b*256 + t] = aq;
        ws[OFF_WCK + b*256 + t] = ak;
        if (t == 0) {
            float av = 0.f;
            for (int d = 0; d < 64; ++d) av = fmaf(Wmv[e*64 + d], bv[h*64 + d], av);
            ws[OFF_BV + b] = av + bmv[e];
        }
    } else {
        __shared__ float pl[3][256];
        int bb = b - 256;
        int z = bb & 15, c = bb >> 4;
        const float* xc = x + (size_t)c*4096;
        #pragma unroll
        for (int kz = 0; kz < 3; ++kz) {
            int zz = z + kz - 1;
            pl[kz][t] = (zz >= 0 && zz < 16) ? xc[zz*256 + t] : 0.f;
        }
        __syncthreads();
        int y = t >> 4, xx = t & 15;
        const float* wc = Wv + c*27;
        float acc = 0.f;
        #pragma unroll
        for (int kz = 0; kz < 3; ++kz) {
            #pragma unroll
            for (int ky = 0; ky < 3; ++ky) {
                int yy = y + ky - 1;
                bool vy = (yy >= 0) && (yy < 16);
                int yc = yy < 0 ? 0 : (yy > 15 ? 15 : yy);
                #pragma unroll
                for (int kx = 0; kx < 3; ++kx) {
                    int xv = xx + kx - 1;
                    bool v = vy && (xv >= 0) && (xv < 16);
                    int xc2 = xv < 0 ? 0 : (xv > 15 ? 15 : xv);
                    float val = pl[kz][yc*16 + xc2];
                    acc = fmaf(wc[(kz*3 + ky)*3 + kx], v ? val : 0.f, acc);
                }
            }
        }
        ws[OFF_VC + (size_t)c*4096 + z*256 + t] = acc;
    }
}

// Per (hb 0..3, chunk of 64 tokens): K-proj GEMM (K=256) + V-proj (K=64,
// block-diag) -> exp± in LDS -> outer products -> atomicAdd into Sm/sv.
__global__ __launch_bounds__(256) void k_kv(
    const float* __restrict__ X, const float* __restrict__ bmk,
    const float* __restrict__ Wmv, float* __restrict__ ws)
{
    __shared__ float smem[16384];   // 64 KB
    float* Xs  = smem;              // [64][64] phase 1
    float* Wsh = smem + 4096;       // [64][68] phase 1
    float* kfp = smem;              // [64][64] phase 2/3 (overlay, barrier-separated)
    float* kfm = smem + 4096;
    float* vfp = smem + 8192;
    float* vfm = smem + 12288;

    int t = threadIdx.x;
    int chunk = blockIdx.x;         // 0..63
    int hb = blockIdx.y;            // 0..3
    int n0 = chunk * 64;
    int lc = t >> 6, ln = t & 63;
    int e4 = (t & 15) * 4;
    int n4 = (t >> 4) * 4;

    float accK[4][4], accV[4][4];
    #pragma unroll
    for (int i = 0; i < 4; ++i)
        #pragma unroll
        for (int j = 0; j < 4; ++j) { accK[i][j] = 0.f; accV[i][j] = 0.f; }

    // ---- K-projection GEMM, K=256 ----
    const float* Wck = ws + OFF_WCK;
    for (int c0 = 0; c0 < 256; c0 += 64) {
        #pragma unroll
        for (int i = 0; i < 16; ++i)
            Xs[(lc*16 + i)*64 + ln] = X[(size_t)(c0 + lc*16 + i)*4096 + n0 + ln];
        #pragma unroll
        for (int i = 0; i < 16; ++i)
            Wsh[ln*68 + lc*16 + i] = Wck[(size_t)(hb*64 + lc*16 + i)*256 + c0 + ln];
        __syncthreads();
        #pragma unroll 4
        for (int c = 0; c < 64; ++c) {
            float4 xv4 = *(const float4*)&Xs[c*64 + n4];
            float4 wv4 = *(const float4*)&Wsh[c*68 + e4];
            float xv[4] = {xv4.x, xv4.y, xv4.z, xv4.w};
            float wv[4] = {wv4.x, wv4.y, wv4.z, wv4.w};
            #pragma unroll
            for (int ii = 0; ii < 4; ++ii)
                #pragma unroll
                for (int jj = 0; jj < 4; ++jj)
                    accK[ii][jj] = fmaf(xv[ii], wv[jj], accK[ii][jj]);
        }
        __syncthreads();
    }

    // ---- V-projection GEMM, K=64 (block-diagonal head) ----
    {
        const float* vcb = ws + OFF_VC + (size_t)hb*64*4096;
        #pragma unroll
        for (int i = 0; i < 16; ++i)
            Xs[(lc*16 + i)*64 + ln] = vcb[(size_t)(lc*16 + i)*4096 + n0 + ln];
        #pragma unroll
        for (int i = 0; i < 16; ++i) {
            int idx = i*256 + t, dd = idx & 63, ee = idx >> 6;
            Wsh[dd*68 + ee] = Wmv[ee*64 + dd];
        }
        __syncthreads();
        #pragma unroll 4
        for (int d = 0; d < 64; ++d) {
            float4 xv4 = *(const float4*)&Xs[d*64 + n4];
            float4 wv4 = *(const float4*)&Wsh[d*68 + e4];
            float xv[4] = {xv4.x, xv4.y, xv4.z, xv4.w};
            float wv[4] = {wv4.x, wv4.y, wv4.z, wv4.w};
            #pragma unroll
            for (int ii = 0; ii < 4; ++ii)
                #pragma unroll
                for (int jj = 0; jj < 4; ++jj)
                    accV[ii][jj] = fmaf(xv[ii], wv[jj], accV[ii][jj]);
        }
        __syncthreads();
    }

    // ---- bias + exp± into LDS [n][a] ----
    float bk[4], bvv[4];
    #pragma unroll
    for (int j = 0; j < 4; ++j) { bk[j] = bmk[e4 + j]; bvv[j] = ws[OFF_BV + hb*64 + e4 + j]; }
    #pragma unroll
    for (int ii = 0; ii < 4; ++ii) {
        float pk[4], mk_[4], pv[4], mv[4];
        #pragma unroll
        for (int jj = 0; jj < 4; ++jj) {
            float a = accK[ii][jj] + bk[jj];
            pk[jj] = __expf(a);  mk_[jj] = __expf(-a);
            float b = accV[ii][jj] + bvv[jj];
            pv[jj] = __expf(b);  mv[jj] = __expf(-b);
        }
        int r = (n4 + ii)*64 + e4;
        *(float4*)&kfp[r] = make_float4(pk[0], pk[1], pk[2], pk[3]);
        *(float4*)&kfm[r] = make_float4(mk_[0], mk_[1], mk_[2], mk_[3]);
        *(float4*)&vfp[r] = make_float4(pv[0], pv[1], pv[2], pv[3]);
        *(float4*)&vfm[r] = make_float4(mv[0], mv[1], mv[2], mv[3]);
    }
    __syncthreads();

    // ---- outer products over 64 tokens ----
    int a4 = e4, f4 = n4;
    float aSp[4][4], aSm[4][4], svp[4], svm[4];
    #pragma unroll
    for (int i = 0; i < 4; ++i) {
        svp[i] = 0.f; svm[i] = 0.f;
        #pragma unroll
        for (int j = 0; j < 4; ++j) { aSp[i][j] = 0.f; aSm[i][j] = 0.f; }
    }
    #pragma unroll 2
    for (int n = 0; n < 64; ++n) {
        float4 kp4 = *(const float4*)&kfp[n*64 + a4];
        float4 km4 = *(const float4*)&kfm[n*64 + a4];
        float4 vp4 = *(const float4*)&vfp[n*64 + f4];
        float4 vm4 = *(const float4*)&vfm[n*64 + f4];
        float kp[4] = {kp4.x, kp4.y, kp4.z, kp4.w};
        float km[4] = {km4.x, km4.y, km4.z, km4.w};
        float vp[4] = {vp4.x, vp4.y, vp4.z, vp4.w};
        float vm[4] = {vm4.x, vm4.y, vm4.z, vm4.w};
        #pragma unroll
        for (int ai = 0; ai < 4; ++ai) {
            svp[ai] += kp[ai];  svm[ai] += km[ai];
            #pragma unroll
            for (int fi = 0; fi < 4; ++fi) {
                aSp[ai][fi] = fmaf(kp[ai], vp[fi], aSp[ai][fi]);
                aSm[ai][fi] = fmaf(km[ai], vm[fi], aSm[ai][fi]);
            }
        }
    }
    // ---- atomic accumulate into Sm / sv ----
    float* Smp = ws + OFF_SM + (size_t)hb*4096;
    float* Smm = ws + OFF_SM + (size_t)(hb + 4)*4096;
    #pragma unroll
    for (int ai = 0; ai < 4; ++ai)
        #pragma unroll
        for (int fi = 0; fi < 4; ++fi) {
            atomicAdd(&Smp[(a4 + ai)*64 + f4 + fi], aSp[ai][fi]);
            atomicAdd(&Smm[(a4 + ai)*64 + f4 + fi], aSm[ai][fi]);
        }
    if (t < 16) {
        #pragma unroll
        for (int i = 0; i < 4; ++i) {
            atomicAdd(&ws[OFF_SV + hb*64 + a4 + i], svp[i]);
            atomicAdd(&ws[OFF_SV + (hb + 4)*64 + a4 + i], svm[i]);
        }
    }
}

// Per (hb, chunk of 64 tokens): Q-proj GEMM -> qf± transposed [a][n] in LDS ->
// out[h] = (qf·Sm[h]) / (qf·sv[h] + eps), h = hb (plus) then hb+4 (minus).
__global__ __launch_bounds__(256) void k_q_out(
    const float* __restrict__ X, const float* __restrict__ bmq,
    const float* __restrict__ ws, float* __restrict__ out)
{
    __shared__ float smem[12544];   // ~50 KB
    float* Xs   = smem;             // [64][64] phase 1
    float* Wsh  = smem + 4096;      // [64][68] phase 1
    float* qfTp = smem;             // [a][n] phase 2/3 (overlay)
    float* qfTm = smem + 4096;
    float* Sms  = smem + 8448;      // [64][64] separate region

    int t = threadIdx.x;
    int chunk = blockIdx.x;         // 0..63
    int hb = blockIdx.y;            // 0..3
    int n0 = chunk * 64;
    int lc = t >> 6, ln = t & 63;
    int a4 = (t & 15) * 4;          // phase-1 e(=a)
    int n4 = (t >> 4) * 4;          // phase-1 n

    // stage Sm[hb] early (separate region; latency hides under the GEMM)
    const float* SgP = ws + OFF_SM + (size_t)hb*4096;
    #pragma unroll
    for (int i = 0; i < 16; ++i) { int idx = i*256 + t; Sms[idx] = SgP[idx]; }

    float accQ[4][4];               // [n][e]
    #pragma unroll
    for (int i = 0; i < 4; ++i)
        #pragma unroll
        for (int j = 0; j < 4; ++j) accQ[i][j] = 0.f;

    const float* Wcq = ws + OFF_WCQ;
    for (int c0 = 0; c0 < 256; c0 += 64) {
        #pragma unroll
        for (int i = 0; i < 16; ++i)
            Xs[(lc*16 + i)*64 + ln] = X[(size_t)(c0 + lc*16 + i)*4096 + n0 + ln];
        #pragma unroll
        for (int i = 0; i < 16; ++i)
            Wsh[ln*68 + lc*16 + i] = Wcq[(size_t)(hb*64 + lc*16 + i)*256 + c0 + ln];
        __syncthreads();
        #pragma unroll 4
        for (int c = 0; c < 64; ++c) {
            float4 xv4 = *(const float4*)&Xs[c*64 + n4];
            float4 wv4 = *(const float4*)&Wsh[c*68 + a4];
            float xv[4] = {xv4.x, xv4.y, xv4.z, xv4.w};
            float wv[4] = {wv4.x, wv4.y, wv4.z, wv4.w};
            #pragma unroll
            for (int ii = 0; ii < 4; ++ii)
                #pragma unroll
                for (int jj = 0; jj < 4; ++jj)
                    accQ[ii][jj] = fmaf(xv[ii], wv[jj], accQ[ii][jj]);
        }
        __syncthreads();
    }

    // exp± into transposed LDS [a][n]
    #pragma unroll
    for (int jj = 0; jj < 4; ++jj) {
        float b = bmq[a4 + jj];
        float v0 = accQ[0][jj] + b, v1 = accQ[1][jj] + b,
              v2 = accQ[2][jj] + b, v3 = accQ[3][jj] + b;
        *(float4*)&qfTp[(a4 + jj)*64 + n4] =
            make_float4(__expf(v0), __expf(v1), __expf(v2), __expf(v3));
        *(float4*)&qfTm[(a4 + jj)*64 + n4] =
            make_float4(__expf(-v0), __expf(-v1), __expf(-v2), __expf(-v3));
    }

    int n4b = (t & 15) * 4;         // phase-3 n (coalesced store)
    int e4b = (t >> 4) * 4;         // phase-3 e
    for (int s = 0; s < 2; ++s) {
        int h = hb + 4*s;
        if (s) {                    // re-stage Sm[hb+4]
            __syncthreads();
            const float* SgM = ws + OFF_SM + (size_t)h*4096;
            #pragma unroll
            for (int i = 0; i < 16; ++i) { int idx = i*256 + t; Sms[idx] = SgM[idx]; }
        }
        __syncthreads();
        const float* qf  = s ? qfTm : qfTp;
        const float* svg = ws + OFF_SV + h*64;   // uniform -> scalar/broadcast loads
        float acc[4][4];            // [e][n]
        float den[4] = {0.f, 0.f, 0.f, 0.f};
        #pragma unroll
        for (int i = 0; i < 4; ++i)
            #pragma unroll
            for (int j = 0; j < 4; ++j) acc[i][j] = 0.f;
        #pragma unroll 4
        for (int a = 0; a < 64; ++a) {
            float4 qv4 = *(const float4*)&qf[a*64 + n4b];
            float4 sm4 = *(const float4*)&Sms[a*64 + e4b];
            float qv[4] = {qv4.x, qv4.y, qv4.z, qv4.w};
            float sm[4] = {sm4.x, sm4.y, sm4.z, sm4.w};
            float sva = svg[a];
            #pragma unroll
            for (int nj = 0; nj < 4; ++nj) {
                den[nj] = fmaf(qv[nj], sva, den[nj]);
                #pragma unroll
                for (int ei = 0; ei < 4; ++ei)
                    acc[ei][nj] = fmaf(sm[ei], qv[nj], acc[ei][nj]);
            }
        }
        float r[4];
        #pragma unroll
        for (int nj = 0; nj < 4; ++nj) r[nj] = 1.f / (den[nj] + EPS_F);
        #pragma unroll
        for (int ei = 0; ei < 4; ++ei)
            *(float4*)&out[(size_t)(h*64 + e4b + ei)*4096 + n0 + n4b] =
                make_float4(acc[ei][0]*r[0], acc[ei][1]*r[1], acc[ei][2]*r[2], acc[ei][3]*r[3]);
    }
}

extern "C" void kernel_launch(void* const* d_in, const int* in_sizes, int n_in,
                              void* d_out, int out_size, void* d_ws, size_t ws_size,
                              hipStream_t stream) {
    const float* x   = (const float*)d_in[0];
    const float* Wq  = (const float*)d_in[1];
    const float* Wk  = (const float*)d_in[2];
    const float* Wv  = (const float*)d_in[3];
    const float* bv  = (const float*)d_in[4];
    const float* Wmq = (const float*)d_in[5];
    const float* bmq = (const float*)d_in[6];
    const float* Wmk = (const float*)d_in[7];
    const float* bmk = (const float*)d_in[8];
    const float* Wmv = (const float*)d_in[9];
    const float* bmv = (const float*)d_in[10];
    float* out = (float*)d_out;
    float* ws  = (float*)d_ws;

    k_prep<<<4352, 256, 0, stream>>>(x, Wv, Wq, Wk, Wmq, Wmk, Wmv, bmv, bv, ws);
    k_kv<<<dim3(64, 4), 256, 0, stream>>>(x, bmk, Wmv, ws);
    k_q_out<<<dim3(64, 4), 256, 0, stream>>>(x, bmq, ws, out);
}